// Round 15
// baseline (91.057 us; speedup 1.0000x reference)
//
#include <hip/hip_runtime.h>
#include <hip/hip_fp16.h>

#define NROUTES 1152
#define NCAPS   10
#define OUTCH   16
#define INCH    8
#define NBATCH  512
#define NITER   3
#define NPROB   (NBATCH * NCAPS)    // 5120
#define NCHUNK  2                   // producer->consumer interleave granularity

// U layout: [prob = b*10+c][half h=0/1][route][8 o] fp16.
//  - k1 store instr: lanes run along route -> 256B dense segments -> FULL 64B
//    lines per instruction -> no L2 write-allocate RMW (round-8 lesson).
//  - k2 reads two coalesced streams at uint4 index r and 1152+r.
// Round 15: k1/k2 interleaved in 2 batch-chunks so each k2 chunk reads the
// 94 MB U slice written by the IMMEDIATELY preceding k1 dispatch -> L3-hot
// (round 13/14: monolithic order let ~92 MB of U fall out of L3 to HBM).

typedef _Float16 h2 __attribute__((ext_vector_type(2)));
typedef _Float16 half8 __attribute__((ext_vector_type(8)));

#if defined(__has_builtin)
#if __has_builtin(__builtin_amdgcn_fdot2)
#define HAVE_FDOT2 1
#endif
#endif

__device__ __forceinline__ float dot2acc(h2 a, h2 b, float c) {
#ifdef HAVE_FDOT2
    return __builtin_amdgcn_fdot2(a, b, c, false);
#else
    return c + (float)a[0] * (float)b[0] + (float)a[1] * (float)b[1];
#endif
}

__device__ __forceinline__ h2 to_h2(float a, float b) {
    __half2 t = __float22half2_rn(make_float2(a, b));
    return *reinterpret_cast<h2*>(&t);
}

// ================= Kernel 1: staging (u_hat -> workspace, fp16) =============
// Body unchanged from rounds 9-14 (write-BW bound at ~4.5 TB/s combined);
// b_base selects the batch chunk.
#define K1_RCH   16
#define K1_BCH   16
#define K1_TPB   256
#define K1_ROWB  2576
#define K1_UNITS (K1_RCH * 320)

__global__ __launch_bounds__(K1_TPB, 3)
void k1_stage(const float* __restrict__ X,   // (R, B, I)
              const float* __restrict__ W,   // (R, C, O, I)
              __half* __restrict__ U,
              int b_base)
{
    const int t  = threadIdx.x;
    const int rl = t & 15;
    const int bl = t >> 4;
    const int r0 = (blockIdx.x % (NROUTES / K1_RCH)) * K1_RCH;
    const int b0 = b_base + (blockIdx.x / (NROUTES / K1_RCH)) * K1_BCH;

    __shared__ __align__(16) unsigned char wlds[K1_RCH * K1_ROWB];  // 41216 B

    {   // stage W tile (16 routes x 5120B f32) -> LDS fp16 (coalesced)
        const float4* src = reinterpret_cast<const float4*>(
            W + (size_t)r0 * NCAPS * OUTCH * INCH);
        #pragma unroll
        for (int k = 0; k < K1_UNITS / K1_TPB; ++k) {   // 20 iters
            const int u      = t + k * K1_TPB;
            const int rseg   = u / 320;
            const int within = u % 320;
            float4 w4 = src[u];
            __half2 lo = __float22half2_rn(make_float2(w4.x, w4.y));
            __half2 hi = __float22half2_rn(make_float2(w4.z, w4.w));
            uint2 pk;
            pk.x = *reinterpret_cast<unsigned int*>(&lo);
            pk.y = *reinterpret_cast<unsigned int*>(&hi);
            *reinterpret_cast<uint2*>(wlds + rseg * K1_ROWB + within * 8) = pk;
        }
    }
    __syncthreads();   // the only barrier in k1

    h2 xh[4];
    {
        const float* xp = X + ((size_t)(r0 + rl) * NBATCH + (b0 + bl)) * INCH;
        float4 xa = *reinterpret_cast<const float4*>(xp);
        float4 xb = *reinterpret_cast<const float4*>(xp + 4);
        xh[0] = to_h2(xa.x, xa.y);
        xh[1] = to_h2(xa.z, xa.w);
        xh[2] = to_h2(xb.x, xb.y);
        xh[3] = to_h2(xb.z, xb.w);
    }

    const unsigned char* wrow = wlds + rl * K1_ROWB;

    for (int c = 0; c < NCAPS; ++c) {
        float acc[OUTCH];
        #pragma unroll
        for (int o = 0; o < OUTCH; ++o) {
            uint4 wv = *reinterpret_cast<const uint4*>(wrow + c * 256 + o * 16);
            const h2* wp = reinterpret_cast<const h2*>(&wv);
            float a = dot2acc(wp[0], xh[0], 0.0f);
            a = dot2acc(wp[1], xh[1], a);
            a = dot2acc(wp[2], xh[2], a);
            a = dot2acc(wp[3], xh[3], a);
            acc[o] = a;
        }
        uint4 pk0, pk1;
        {
            unsigned int* q0 = reinterpret_cast<unsigned int*>(&pk0);
            unsigned int* q1 = reinterpret_cast<unsigned int*>(&pk1);
            #pragma unroll
            for (int j = 0; j < 4; ++j) {
                __half2 a0 = __float22half2_rn(make_float2(acc[2 * j],     acc[2 * j + 1]));
                __half2 a1 = __float22half2_rn(make_float2(acc[8 + 2 * j], acc[9 + 2 * j]));
                q0[j] = *reinterpret_cast<unsigned int*>(&a0);
                q1[j] = *reinterpret_cast<unsigned int*>(&a1);
            }
        }
        const size_t prob = (size_t)(b0 + bl) * NCAPS + c;
        uint4* ub = reinterpret_cast<uint4*>(U + prob * (2 * NROUTES * 8));
        ub[r0 + rl]           = pk0;   // half 0: o0..o7
        ub[NROUTES + r0 + rl] = pk1;   // half 1: o8..o15
    }
}

// ================= Kernel 2: routing =========================================
// Body unchanged from round 14 (TPB 192 / RPT 6, launch_bounds(192,1) -> no
// spill, ~33us); p_base selects the problem chunk.
#define K2_TPB  192                 // 3 waves
#define K2_RPT  (NROUTES / K2_TPB)  // 6 routes per thread
#define K2_NW   (K2_TPB / 64)

__global__ __launch_bounds__(K2_TPB, 1)
void k2_route(const __half* __restrict__ U, float* __restrict__ OUT, int p_base)
{
    const int t    = threadIdx.x;
    const int wid  = t >> 6;
    const int lane = t & 63;
    const int p    = p_base + blockIdx.x;

    __shared__ float red[K2_NW][17];
    __shared__ float fin[17];

    // load u: routes r = k*192 + t; two coalesced half-streams (48 VGPRs, packed)
    uint4 upk[K2_RPT][2];
    {
        const uint4* ub = reinterpret_cast<const uint4*>(U + (size_t)p * (2 * NROUTES * 8));
        #pragma unroll
        for (int k = 0; k < K2_RPT; ++k) {
            upk[k][0] = ub[k * K2_TPB + t];
            upk[k][1] = ub[NROUTES + k * K2_TPB + t];
        }
    }

    float bij[K2_RPT];
    #pragma unroll
    for (int k = 0; k < K2_RPT; ++k) bij[k] = 0.0f;
    float v[OUTCH];

    #pragma unroll
    for (int it = 0; it < NITER; ++it) {
        float S[OUTCH];
        float Z = 0.0f;
        #pragma unroll
        for (int o = 0; o < OUTCH; ++o) S[o] = 0.0f;

        // fused pass: (b-update + exp) + S accumulate; f16 lanes extended in
        // the FMA itself (mad-mix peephole).
        #pragma unroll
        for (int k = 0; k < K2_RPT; ++k) {
            half8 ha, hb;
            __builtin_memcpy(&ha, &upk[k][0], 16);
            __builtin_memcpy(&hb, &upk[k][1], 16);
            if (it == 0) {
                #pragma unroll
                for (int j = 0; j < 8; ++j) {
                    S[j]     += (float)ha[j];
                    S[8 + j] += (float)hb[j];
                }
            } else {
                float d = 0.0f;
                #pragma unroll
                for (int j = 0; j < 8; ++j) {
                    d = fmaf((float)ha[j], v[j],     d);
                    d = fmaf((float)hb[j], v[8 + j], d);
                }
                bij[k] += d;
                float e = __expf(bij[k]);
                Z += e;
                #pragma unroll
                for (int j = 0; j < 8; ++j) {
                    S[j]     = fmaf((float)ha[j], e, S[j]);
                    S[8 + j] = fmaf((float)hb[j], e, S[8 + j]);
                }
            }
        }

        // scatter-halving wave reduce: 17 shuffles for S[16]
        float s;
        {
            float a8[8];
            {
                const int bit = lane & 1;
                #pragma unroll
                for (int i = 0; i < 8; ++i)
                    a8[i] = (bit ? S[i + 8] : S[i]) +
                            __shfl_xor(bit ? S[i] : S[i + 8], 1);
            }
            float a4[4];
            {
                const int bit = lane & 2;
                #pragma unroll
                for (int i = 0; i < 4; ++i)
                    a4[i] = (bit ? a8[i + 4] : a8[i]) +
                            __shfl_xor(bit ? a8[i] : a8[i + 4], 2);
            }
            float a2[2];
            {
                const int bit = lane & 4;
                #pragma unroll
                for (int i = 0; i < 2; ++i)
                    a2[i] = (bit ? a4[i + 2] : a4[i]) +
                            __shfl_xor(bit ? a4[i] : a4[i + 2], 4);
            }
            {
                const int bit = lane & 8;
                s = (bit ? a2[1] : a2[0]) + __shfl_xor(bit ? a2[0] : a2[1], 8);
            }
            s += __shfl_xor(s, 16);
            s += __shfl_xor(s, 32);
        }
        if (it > 0) {
            #pragma unroll
            for (int sh = 1; sh <= 32; sh <<= 1) Z += __shfl_xor(Z, sh);
        }

        if (lane < 16) {
            const int o = ((lane & 1) << 3) | ((lane & 2) << 1) |
                          ((lane & 4) >> 1) | ((lane & 8) >> 3);
            red[wid][o] = s;
        } else if (lane == 16) {
            red[wid][16] = Z;
        }
        __syncthreads();   // B1

        if (t < 17) {
            float ss = red[0][t];
            #pragma unroll
            for (int w = 1; w < K2_NW; ++w) ss += red[w][t];
            fin[t] = ss;
        }
        __syncthreads();   // B2

        // squash (redundant per thread; broadcast from LDS)
        {
            float rZ = (it == 0) ? (1.0f / 1152.0f) : (1.0f / fin[16]);
            float n2 = 0.0f;
            #pragma unroll
            for (int o = 0; o < OUTCH; ++o) {
                float sv = fin[o] * rZ;
                v[o] = sv;
                n2 = fmaf(sv, sv, n2);
            }
            float sc = sqrtf(n2) / (1.0f + n2);
            #pragma unroll
            for (int o = 0; o < OUTCH; ++o) v[o] *= sc;
        }
        // red/fin reuse next iter ordered by next iter's B1/B2.
    }

    if (t == 0) {
        float* op = OUT + (size_t)p * OUTCH;
        #pragma unroll
        for (int o = 0; o < OUTCH; o += 4)
            *reinterpret_cast<float4*>(op + o) =
                make_float4(v[o], v[o + 1], v[o + 2], v[o + 3]);
    }
}

extern "C" void kernel_launch(void* const* d_in, const int* in_sizes, int n_in,
                              void* d_out, int out_size, void* d_ws, size_t ws_size,
                              hipStream_t stream) {
    const float* X = (const float*)d_in[0];            // (1152, 512, 8)
    const float* W = (const float*)d_in[1];            // (1152, 10, 16, 8)
    float* OUT     = (float*)d_out;                    // (512, 10, 16)
    __half* U      = (__half*)d_ws;                    // 188.7 MB (fits ws)

    const int BCH = NBATCH / NCHUNK;                   // 256 batches per chunk
    for (int g = 0; g < NCHUNK; ++g) {
        const int b_base = g * BCH;
        k1_stage<<<dim3((NROUTES / K1_RCH) * (BCH / K1_BCH)), dim3(K1_TPB), 0, stream>>>(
            X, W, U, b_base);
        k2_route<<<dim3(BCH * NCAPS), dim3(K2_TPB), 0, stream>>>(
            U, OUT, b_base * NCAPS);
    }
}

// Round 16
// 79.262 us; speedup vs baseline: 1.1488x; 1.1488x over previous
//
#include <hip/hip_runtime.h>
#include <hip/hip_fp16.h>

#define NROUTES 1152
#define NCAPS   10
#define OUTCH   16
#define INCH    8
#define NBATCH  512
#define NITER   3
#define NPROB   (NBATCH * NCAPS)    // 5120

// U layout: [prob = b*10+c][half h=0/1][route][8 o] fp16.
//  - k1 store instr: lanes run along route -> 256B dense segments -> FULL 64B
//    lines per instruction -> no L2 write-allocate RMW (round-8 lesson).
//  - k2 reads two coalesced streams at uint4 index r and 1152+r.
// Round 16 = round 14 (best: 80.4us) + k2 squash computed by wave-0 lanes 0-15
// only (v broadcast via LDS) instead of redundantly by all 192 threads.
// Round-15 chunked-interleave REVERTED: 4 dispatch boundaries cost ~11us and
// the harness's 268MB between-replay fills void cross-kernel L3 locality.

typedef _Float16 h2 __attribute__((ext_vector_type(2)));
typedef _Float16 half8 __attribute__((ext_vector_type(8)));

#if defined(__has_builtin)
#if __has_builtin(__builtin_amdgcn_fdot2)
#define HAVE_FDOT2 1
#endif
#endif

__device__ __forceinline__ float dot2acc(h2 a, h2 b, float c) {
#ifdef HAVE_FDOT2
    return __builtin_amdgcn_fdot2(a, b, c, false);
#else
    return c + (float)a[0] * (float)b[0] + (float)a[1] * (float)b[1];
#endif
}

__device__ __forceinline__ h2 to_h2(float a, float b) {
    __half2 t = __float22half2_rn(make_float2(a, b));
    return *reinterpret_cast<h2*>(&t);
}

// ================= Kernel 1: staging (u_hat -> workspace, fp16) =============
// Unchanged from rounds 9-14 (measured ~47us; write 184 MB at ~4.0 TB/s —
// above the copy benchmark's per-direction rate -> at the write ceiling).
#define K1_RCH   16
#define K1_BCH   16
#define K1_TPB   256
#define K1_ROWB  2576
#define K1_UNITS (K1_RCH * 320)

__global__ __launch_bounds__(K1_TPB, 3)
void k1_stage(const float* __restrict__ X,   // (R, B, I)
              const float* __restrict__ W,   // (R, C, O, I)
              __half* __restrict__ U)
{
    const int t  = threadIdx.x;
    const int rl = t & 15;
    const int bl = t >> 4;
    const int r0 = (blockIdx.x % (NROUTES / K1_RCH)) * K1_RCH;
    const int b0 = (blockIdx.x / (NROUTES / K1_RCH)) * K1_BCH;

    __shared__ __align__(16) unsigned char wlds[K1_RCH * K1_ROWB];  // 41216 B

    {   // stage W tile (16 routes x 5120B f32) -> LDS fp16 (coalesced)
        const float4* src = reinterpret_cast<const float4*>(
            W + (size_t)r0 * NCAPS * OUTCH * INCH);
        #pragma unroll
        for (int k = 0; k < K1_UNITS / K1_TPB; ++k) {   // 20 iters
            const int u      = t + k * K1_TPB;
            const int rseg   = u / 320;
            const int within = u % 320;
            float4 w4 = src[u];
            __half2 lo = __float22half2_rn(make_float2(w4.x, w4.y));
            __half2 hi = __float22half2_rn(make_float2(w4.z, w4.w));
            uint2 pk;
            pk.x = *reinterpret_cast<unsigned int*>(&lo);
            pk.y = *reinterpret_cast<unsigned int*>(&hi);
            *reinterpret_cast<uint2*>(wlds + rseg * K1_ROWB + within * 8) = pk;
        }
    }
    __syncthreads();   // the only barrier in k1

    h2 xh[4];
    {
        const float* xp = X + ((size_t)(r0 + rl) * NBATCH + (b0 + bl)) * INCH;
        float4 xa = *reinterpret_cast<const float4*>(xp);
        float4 xb = *reinterpret_cast<const float4*>(xp + 4);
        xh[0] = to_h2(xa.x, xa.y);
        xh[1] = to_h2(xa.z, xa.w);
        xh[2] = to_h2(xb.x, xb.y);
        xh[3] = to_h2(xb.z, xb.w);
    }

    const unsigned char* wrow = wlds + rl * K1_ROWB;

    for (int c = 0; c < NCAPS; ++c) {
        float acc[OUTCH];
        #pragma unroll
        for (int o = 0; o < OUTCH; ++o) {
            uint4 wv = *reinterpret_cast<const uint4*>(wrow + c * 256 + o * 16);
            const h2* wp = reinterpret_cast<const h2*>(&wv);
            float a = dot2acc(wp[0], xh[0], 0.0f);
            a = dot2acc(wp[1], xh[1], a);
            a = dot2acc(wp[2], xh[2], a);
            a = dot2acc(wp[3], xh[3], a);
            acc[o] = a;
        }
        uint4 pk0, pk1;
        {
            unsigned int* q0 = reinterpret_cast<unsigned int*>(&pk0);
            unsigned int* q1 = reinterpret_cast<unsigned int*>(&pk1);
            #pragma unroll
            for (int j = 0; j < 4; ++j) {
                __half2 a0 = __float22half2_rn(make_float2(acc[2 * j],     acc[2 * j + 1]));
                __half2 a1 = __float22half2_rn(make_float2(acc[8 + 2 * j], acc[9 + 2 * j]));
                q0[j] = *reinterpret_cast<unsigned int*>(&a0);
                q1[j] = *reinterpret_cast<unsigned int*>(&a1);
            }
        }
        const size_t prob = (size_t)(b0 + bl) * NCAPS + c;
        uint4* ub = reinterpret_cast<uint4*>(U + prob * (2 * NROUTES * 8));
        ub[r0 + rl]           = pk0;   // half 0: o0..o7
        ub[NROUTES + r0 + rl] = pk1;   // half 1: o8..o15
    }
}

// ================= Kernel 2: routing =========================================
// Round-14 shape (TPB 192 / RPT 6, launch_bounds(192,1) -> no spill, reverse
// problem order for L3 tail-freshness) + wave-0 squash.
#define K2_TPB  192                 // 3 waves
#define K2_RPT  (NROUTES / K2_TPB)  // 6 routes per thread
#define K2_NW   (K2_TPB / 64)

__global__ __launch_bounds__(K2_TPB, 1)
void k2_route(const __half* __restrict__ U, float* __restrict__ OUT)
{
    const int t    = threadIdx.x;
    const int wid  = t >> 6;
    const int lane = t & 63;
    const int p    = (NPROB - 1) - blockIdx.x;   // reverse: L3 temporal locality

    __shared__ float red[K2_NW][17];
    __shared__ float finZ;                       // block-total Z
    __shared__ __align__(16) float vbuf[OUTCH];  // squashed v (wave-0 computed)

    // load u: routes r = k*192 + t; two coalesced half-streams (48 VGPRs, packed)
    uint4 upk[K2_RPT][2];
    {
        const uint4* ub = reinterpret_cast<const uint4*>(U + (size_t)p * (2 * NROUTES * 8));
        #pragma unroll
        for (int k = 0; k < K2_RPT; ++k) {
            upk[k][0] = ub[k * K2_TPB + t];
            upk[k][1] = ub[NROUTES + k * K2_TPB + t];
        }
    }

    float bij[K2_RPT];
    #pragma unroll
    for (int k = 0; k < K2_RPT; ++k) bij[k] = 0.0f;
    float v[OUTCH];

    #pragma unroll
    for (int it = 0; it < NITER; ++it) {
        float S[OUTCH];
        float Z = 0.0f;
        #pragma unroll
        for (int o = 0; o < OUTCH; ++o) S[o] = 0.0f;

        // fused pass: (b-update + exp) + S accumulate; f16 lanes extended in
        // the FMA itself (mad-mix peephole).
        #pragma unroll
        for (int k = 0; k < K2_RPT; ++k) {
            half8 ha, hb;
            __builtin_memcpy(&ha, &upk[k][0], 16);
            __builtin_memcpy(&hb, &upk[k][1], 16);
            if (it == 0) {
                #pragma unroll
                for (int j = 0; j < 8; ++j) {
                    S[j]     += (float)ha[j];
                    S[8 + j] += (float)hb[j];
                }
            } else {
                float d = 0.0f;
                #pragma unroll
                for (int j = 0; j < 8; ++j) {
                    d = fmaf((float)ha[j], v[j],     d);
                    d = fmaf((float)hb[j], v[8 + j], d);
                }
                bij[k] += d;
                float e = __expf(bij[k]);
                Z += e;
                #pragma unroll
                for (int j = 0; j < 8; ++j) {
                    S[j]     = fmaf((float)ha[j], e, S[j]);
                    S[8 + j] = fmaf((float)hb[j], e, S[8 + j]);
                }
            }
        }

        // scatter-halving wave reduce: 17 shuffles for S[16]
        float s;
        {
            float a8[8];
            {
                const int bit = lane & 1;
                #pragma unroll
                for (int i = 0; i < 8; ++i)
                    a8[i] = (bit ? S[i + 8] : S[i]) +
                            __shfl_xor(bit ? S[i] : S[i + 8], 1);
            }
            float a4[4];
            {
                const int bit = lane & 2;
                #pragma unroll
                for (int i = 0; i < 4; ++i)
                    a4[i] = (bit ? a8[i + 4] : a8[i]) +
                            __shfl_xor(bit ? a8[i] : a8[i + 4], 2);
            }
            float a2[2];
            {
                const int bit = lane & 4;
                #pragma unroll
                for (int i = 0; i < 2; ++i)
                    a2[i] = (bit ? a4[i + 2] : a4[i]) +
                            __shfl_xor(bit ? a4[i] : a4[i + 2], 4);
            }
            {
                const int bit = lane & 8;
                s = (bit ? a2[1] : a2[0]) + __shfl_xor(bit ? a2[0] : a2[1], 8);
            }
            s += __shfl_xor(s, 16);
            s += __shfl_xor(s, 32);
        }
        if (it > 0) {
            #pragma unroll
            for (int sh = 1; sh <= 32; sh <<= 1) Z += __shfl_xor(Z, sh);
        }

        if (lane < 16) {
            const int o = ((lane & 1) << 3) | ((lane & 2) << 1) |
                          ((lane & 4) >> 1) | ((lane & 8) >> 3);
            red[wid][o] = s;
        } else if (lane == 16) {
            red[wid][16] = Z;
        }
        __syncthreads();   // B1

        // cross-wave totals on t<17; only Z goes back through LDS
        float ss = 0.0f;
        if (t < 17) {
            ss = red[0][t];
            #pragma unroll
            for (int w = 1; w < K2_NW; ++w) ss += red[w][t];
            if (t == 16) finZ = ss;
        }
        __syncthreads();   // B2 (finZ visible)

        // squash on wave-0 lanes 0-15 only (lane t owns output channel t)
        if (t < 16) {
            float rZ = (it == 0) ? (1.0f / 1152.0f) : (1.0f / finZ);
            float sv = ss * rZ;
            float n2 = sv * sv;
            n2 += __shfl_xor(n2, 1);
            n2 += __shfl_xor(n2, 2);
            n2 += __shfl_xor(n2, 4);
            n2 += __shfl_xor(n2, 8);
            float sc = sqrtf(n2) / (1.0f + n2);
            vbuf[t] = sv * sc;
        }
        __syncthreads();   // B3 (vbuf visible)

        // broadcast v to registers (4x float4 LDS broadcast reads)
        #pragma unroll
        for (int q = 0; q < 4; ++q) {
            float4 vv = *reinterpret_cast<const float4*>(&vbuf[q * 4]);
            v[q * 4 + 0] = vv.x;
            v[q * 4 + 1] = vv.y;
            v[q * 4 + 2] = vv.z;
            v[q * 4 + 3] = vv.w;
        }
        // red/finZ/vbuf reuse next iter is ordered by next iter's B1/B2.
    }

    if (t == 0) {
        float* op = OUT + (size_t)p * OUTCH;
        #pragma unroll
        for (int o = 0; o < OUTCH; o += 4)
            *reinterpret_cast<float4*>(op + o) =
                make_float4(v[o], v[o + 1], v[o + 2], v[o + 3]);
    }
}

extern "C" void kernel_launch(void* const* d_in, const int* in_sizes, int n_in,
                              void* d_out, int out_size, void* d_ws, size_t ws_size,
                              hipStream_t stream) {
    const float* X = (const float*)d_in[0];            // (1152, 512, 8)
    const float* W = (const float*)d_in[1];            // (1152, 10, 16, 8)
    float* OUT     = (float*)d_out;                    // (512, 10, 16)
    __half* U      = (__half*)d_ws;                    // 188.7 MB (fits ws)

    k1_stage<<<dim3((NROUTES / K1_RCH) * (NBATCH / K1_BCH)), dim3(K1_TPB), 0, stream>>>(X, W, U);
    k2_route<<<dim3(NPROB), dim3(K2_TPB), 0, stream>>>(U, OUT);
}

// Round 17
// 77.305 us; speedup vs baseline: 1.1779x; 1.0253x over previous
//
#include <hip/hip_runtime.h>
#include <hip/hip_fp16.h>

#define NROUTES 1152
#define NCAPS   10
#define OUTCH   16
#define INCH    8
#define NBATCH  512
#define NITER   3
#define NPROB   (NBATCH * NCAPS)    // 5120

// U layout: [prob = b*10+c][half h=0/1][route][8 o] fp16.
//  - k1 store instr: lanes run along route -> dense 128B segments -> FULL 64B
//    lines per instruction -> no L2 write-allocate RMW (round-8 lesson).
//  - k2 reads two coalesced streams at uint4 index r and 1152+r.
// Round 17: k1 LDS 41.5KB -> 20.6KB (RCH 16->8, BCH 16->32) => 7 blocks/CU
// instead of ~3 => deeper store pipelining. Round-16 evidence: harness fill
// kernel writes at 6.6 TB/s vs k1's 4.4 combined at 25% occupancy.

typedef _Float16 h2 __attribute__((ext_vector_type(2)));
typedef _Float16 half8 __attribute__((ext_vector_type(8)));

#if defined(__has_builtin)
#if __has_builtin(__builtin_amdgcn_fdot2)
#define HAVE_FDOT2 1
#endif
#endif

__device__ __forceinline__ float dot2acc(h2 a, h2 b, float c) {
#ifdef HAVE_FDOT2
    return __builtin_amdgcn_fdot2(a, b, c, false);
#else
    return c + (float)a[0] * (float)b[0] + (float)a[1] * (float)b[1];
#endif
}

__device__ __forceinline__ h2 to_h2(float a, float b) {
    __half2 t = __float22half2_rn(make_float2(a, b));
    return *reinterpret_cast<h2*>(&t);
}

// ================= Kernel 1: staging (u_hat -> workspace, fp16) =============
#define K1_RCH   8                   // routes per block (was 16)
#define K1_BCH   32                  // batches per block (was 16)
#define K1_TPB   256                 // 8 rl x 32 bl
#define K1_ROWB  2576                // LDS bytes per route row (2560 fp16 + 16 pad)
#define K1_UNITS (K1_RCH * 320)      // 16B f32 units in W tile: 2560

__global__ __launch_bounds__(K1_TPB, 4)
void k1_stage(const float* __restrict__ X,   // (R, B, I)
              const float* __restrict__ W,   // (R, C, O, I)
              __half* __restrict__ U)
{
    const int t  = threadIdx.x;
    const int rl = t & 7;
    const int bl = t >> 3;
    const int r0 = (blockIdx.x % (NROUTES / K1_RCH)) * K1_RCH;
    const int b0 = (blockIdx.x / (NROUTES / K1_RCH)) * K1_BCH;

    __shared__ __align__(16) unsigned char wlds[K1_RCH * K1_ROWB];  // 20608 B

    {   // stage W tile (8 routes x 5120B f32) -> LDS fp16 (coalesced)
        const float4* src = reinterpret_cast<const float4*>(
            W + (size_t)r0 * NCAPS * OUTCH * INCH);
        #pragma unroll
        for (int k = 0; k < K1_UNITS / K1_TPB; ++k) {   // 10 iters
            const int u      = t + k * K1_TPB;
            const int rseg   = u / 320;
            const int within = u % 320;
            float4 w4 = src[u];
            __half2 lo = __float22half2_rn(make_float2(w4.x, w4.y));
            __half2 hi = __float22half2_rn(make_float2(w4.z, w4.w));
            uint2 pk;
            pk.x = *reinterpret_cast<unsigned int*>(&lo);
            pk.y = *reinterpret_cast<unsigned int*>(&hi);
            *reinterpret_cast<uint2*>(wlds + rseg * K1_ROWB + within * 8) = pk;
        }
    }
    __syncthreads();   // the only barrier in k1

    h2 xh[4];
    {
        const float* xp = X + ((size_t)(r0 + rl) * NBATCH + (b0 + bl)) * INCH;
        float4 xa = *reinterpret_cast<const float4*>(xp);
        float4 xb = *reinterpret_cast<const float4*>(xp + 4);
        xh[0] = to_h2(xa.x, xa.y);
        xh[1] = to_h2(xa.z, xa.w);
        xh[2] = to_h2(xb.x, xb.y);
        xh[3] = to_h2(xb.z, xb.w);
    }

    const unsigned char* wrow = wlds + rl * K1_ROWB;

    for (int c = 0; c < NCAPS; ++c) {
        float acc[OUTCH];
        #pragma unroll
        for (int o = 0; o < OUTCH; ++o) {
            uint4 wv = *reinterpret_cast<const uint4*>(wrow + c * 256 + o * 16);
            const h2* wp = reinterpret_cast<const h2*>(&wv);
            float a = dot2acc(wp[0], xh[0], 0.0f);
            a = dot2acc(wp[1], xh[1], a);
            a = dot2acc(wp[2], xh[2], a);
            a = dot2acc(wp[3], xh[3], a);
            acc[o] = a;
        }
        uint4 pk0, pk1;
        {
            unsigned int* q0 = reinterpret_cast<unsigned int*>(&pk0);
            unsigned int* q1 = reinterpret_cast<unsigned int*>(&pk1);
            #pragma unroll
            for (int j = 0; j < 4; ++j) {
                __half2 a0 = __float22half2_rn(make_float2(acc[2 * j],     acc[2 * j + 1]));
                __half2 a1 = __float22half2_rn(make_float2(acc[8 + 2 * j], acc[9 + 2 * j]));
                q0[j] = *reinterpret_cast<unsigned int*>(&a0);
                q1[j] = *reinterpret_cast<unsigned int*>(&a1);
            }
        }
        const size_t prob = (size_t)(b0 + bl) * NCAPS + c;
        uint4* ub = reinterpret_cast<uint4*>(U + prob * (2 * NROUTES * 8));
        ub[r0 + rl]           = pk0;   // half 0: o0..o7
        ub[NROUTES + r0 + rl] = pk1;   // half 1: o8..o15
    }
}

// ================= Kernel 2: routing =========================================
// Unchanged from round 16 (TPB 192 / RPT 6 / wave-0 squash / reverse order).
#define K2_TPB  192                 // 3 waves
#define K2_RPT  (NROUTES / K2_TPB)  // 6 routes per thread
#define K2_NW   (K2_TPB / 64)

__global__ __launch_bounds__(K2_TPB, 1)
void k2_route(const __half* __restrict__ U, float* __restrict__ OUT)
{
    const int t    = threadIdx.x;
    const int wid  = t >> 6;
    const int lane = t & 63;
    const int p    = (NPROB - 1) - blockIdx.x;   // reverse: L3 temporal locality

    __shared__ float red[K2_NW][17];
    __shared__ float finZ;
    __shared__ __align__(16) float vbuf[OUTCH];

    uint4 upk[K2_RPT][2];
    {
        const uint4* ub = reinterpret_cast<const uint4*>(U + (size_t)p * (2 * NROUTES * 8));
        #pragma unroll
        for (int k = 0; k < K2_RPT; ++k) {
            upk[k][0] = ub[k * K2_TPB + t];
            upk[k][1] = ub[NROUTES + k * K2_TPB + t];
        }
    }

    float bij[K2_RPT];
    #pragma unroll
    for (int k = 0; k < K2_RPT; ++k) bij[k] = 0.0f;
    float v[OUTCH];

    #pragma unroll
    for (int it = 0; it < NITER; ++it) {
        float S[OUTCH];
        float Z = 0.0f;
        #pragma unroll
        for (int o = 0; o < OUTCH; ++o) S[o] = 0.0f;

        #pragma unroll
        for (int k = 0; k < K2_RPT; ++k) {
            half8 ha, hb;
            __builtin_memcpy(&ha, &upk[k][0], 16);
            __builtin_memcpy(&hb, &upk[k][1], 16);
            if (it == 0) {
                #pragma unroll
                for (int j = 0; j < 8; ++j) {
                    S[j]     += (float)ha[j];
                    S[8 + j] += (float)hb[j];
                }
            } else {
                float d = 0.0f;
                #pragma unroll
                for (int j = 0; j < 8; ++j) {
                    d = fmaf((float)ha[j], v[j],     d);
                    d = fmaf((float)hb[j], v[8 + j], d);
                }
                bij[k] += d;
                float e = __expf(bij[k]);
                Z += e;
                #pragma unroll
                for (int j = 0; j < 8; ++j) {
                    S[j]     = fmaf((float)ha[j], e, S[j]);
                    S[8 + j] = fmaf((float)hb[j], e, S[8 + j]);
                }
            }
        }

        // scatter-halving wave reduce: 17 shuffles for S[16]
        float s;
        {
            float a8[8];
            {
                const int bit = lane & 1;
                #pragma unroll
                for (int i = 0; i < 8; ++i)
                    a8[i] = (bit ? S[i + 8] : S[i]) +
                            __shfl_xor(bit ? S[i] : S[i + 8], 1);
            }
            float a4[4];
            {
                const int bit = lane & 2;
                #pragma unroll
                for (int i = 0; i < 4; ++i)
                    a4[i] = (bit ? a8[i + 4] : a8[i]) +
                            __shfl_xor(bit ? a8[i] : a8[i + 4], 2);
            }
            float a2[2];
            {
                const int bit = lane & 4;
                #pragma unroll
                for (int i = 0; i < 2; ++i)
                    a2[i] = (bit ? a4[i + 2] : a4[i]) +
                            __shfl_xor(bit ? a4[i] : a4[i + 2], 4);
            }
            {
                const int bit = lane & 8;
                s = (bit ? a2[1] : a2[0]) + __shfl_xor(bit ? a2[0] : a2[1], 8);
            }
            s += __shfl_xor(s, 16);
            s += __shfl_xor(s, 32);
        }
        if (it > 0) {
            #pragma unroll
            for (int sh = 1; sh <= 32; sh <<= 1) Z += __shfl_xor(Z, sh);
        }

        if (lane < 16) {
            const int o = ((lane & 1) << 3) | ((lane & 2) << 1) |
                          ((lane & 4) >> 1) | ((lane & 8) >> 3);
            red[wid][o] = s;
        } else if (lane == 16) {
            red[wid][16] = Z;
        }
        __syncthreads();   // B1

        float ss = 0.0f;
        if (t < 17) {
            ss = red[0][t];
            #pragma unroll
            for (int w = 1; w < K2_NW; ++w) ss += red[w][t];
            if (t == 16) finZ = ss;
        }
        __syncthreads();   // B2

        if (t < 16) {
            float rZ = (it == 0) ? (1.0f / 1152.0f) : (1.0f / finZ);
            float sv = ss * rZ;
            float n2 = sv * sv;
            n2 += __shfl_xor(n2, 1);
            n2 += __shfl_xor(n2, 2);
            n2 += __shfl_xor(n2, 4);
            n2 += __shfl_xor(n2, 8);
            float sc = sqrtf(n2) / (1.0f + n2);
            vbuf[t] = sv * sc;
        }
        __syncthreads();   // B3

        #pragma unroll
        for (int q = 0; q < 4; ++q) {
            float4 vv = *reinterpret_cast<const float4*>(&vbuf[q * 4]);
            v[q * 4 + 0] = vv.x;
            v[q * 4 + 1] = vv.y;
            v[q * 4 + 2] = vv.z;
            v[q * 4 + 3] = vv.w;
        }
    }

    if (t == 0) {
        float* op = OUT + (size_t)p * OUTCH;
        #pragma unroll
        for (int o = 0; o < OUTCH; o += 4)
            *reinterpret_cast<float4*>(op + o) =
                make_float4(v[o], v[o + 1], v[o + 2], v[o + 3]);
    }
}

extern "C" void kernel_launch(void* const* d_in, const int* in_sizes, int n_in,
                              void* d_out, int out_size, void* d_ws, size_t ws_size,
                              hipStream_t stream) {
    const float* X = (const float*)d_in[0];            // (1152, 512, 8)
    const float* W = (const float*)d_in[1];            // (1152, 10, 16, 8)
    float* OUT     = (float*)d_out;                    // (512, 10, 16)
    __half* U      = (__half*)d_ws;                    // 188.7 MB (fits ws)

    k1_stage<<<dim3((NROUTES / K1_RCH) * (NBATCH / K1_BCH)), dim3(K1_TPB), 0, stream>>>(X, W, U);
    k2_route<<<dim3(NPROB), dim3(K2_TPB), 0, stream>>>(U, OUT);
}